// Round 5
// baseline (170.306 us; speedup 1.0000x reference)
//
#include <hip/hip_runtime.h>

#define NPIX 16384   // 128*128
#define NN   256     // max_nodes
#define CC   256     // NFEAT
#define HH   128     // SCORER_HIDDEN
#define EE   65280   // NN*(NN-1)
#define BB   4
#define NG   8       // histogram privatization groups
#define RR   2       // rows per thread in k_uv

// ---------------- Kernel 1: sigmoid + exact top-k via register radix select ----------------
// key = (float_bits(prob) << 32) | (0xFFFFFFFF - idx)  -- unique per pixel
// top-256 keys descending => prob desc, ties -> lower idx first (matches jax.lax.top_k)
// Also zeroes Sbuf (4 layer colsum buffers) -- replaces a 39.6us hipMemsetAsync dispatch.
__global__ __launch_bounds__(1024) void k_topk(
    const float* __restrict__ jl, const float* __restrict__ off,
    int* __restrict__ topi, int* __restrict__ valid, float* __restrict__ inv_deg,
    float* __restrict__ out_nodes, float* __restrict__ Sbuf)
{
  __shared__ int hist[NG][257];                 // padded: group copies on distinct banks
  __shared__ int histT[256];
  __shared__ unsigned long long s_sel[NN];
  __shared__ unsigned long long s_T;
  __shared__ int s_digit, s_krem, s_cnt, s_vcnt, s_break;

  const int b = blockIdx.x;
  const int tid = threadIdx.x;
  const int grp = (tid >> 7) & (NG - 1);
  if (tid == 0) { s_cnt = 0; s_vcnt = 0; }

  // zero the 4 colsum buffers for this image (layout: Sbuf[l*BB*CC + b*CC + c])
  {
    int l = tid >> 8, c = tid & 255;
    Sbuf[l*BB*CC + b*CC + c] = 0.0f;
  }

  // ---- keys in registers: 16 per thread, coalesced stride-1024 loads ----
  unsigned long long rk[16];
  const float* p = jl + (size_t)b * NPIX;
  #pragma unroll
  for (int r = 0; r < 16; ++r) {
    int i = tid + (r << 10);
    float x = p[i];
    float pr = 1.0f / (1.0f + expf(-x));
    unsigned bits = __float_as_uint(pr);        // prob in (0,1]: bits monotone
    rk[r] = ((unsigned long long)bits << 32) | (unsigned)(0xFFFFFFFFu - (unsigned)i);
  }

  // ---- radix select: find T = 256th largest key ----
  unsigned long long prefix = 0;
  int k = NN;
  int shift = 56;
  int brk = 0;
  for (int pass = 0; pass < 8 && !brk; ++pass) {
    shift = 56 - 8 * pass;
    for (int i = tid; i < NG * 257; i += 1024) ((int*)hist)[i] = 0;
    __syncthreads();
    unsigned long long pmask = (pass == 0) ? 0ULL : (~0ULL << (shift + 8));
    #pragma unroll
    for (int r = 0; r < 16; ++r) {
      unsigned long long kk = rk[r];
      if ((kk & pmask) == prefix)
        atomicAdd(&hist[grp][(int)((kk >> shift) & 255)], 1);
    }
    __syncthreads();
    if (tid < 256) {
      int t = 0;
      #pragma unroll
      for (int g = 0; g < NG; ++g) t += hist[g][tid];
      histT[tid] = t;
    }
    __syncthreads();
    // wave 0: suffix scan over 256 bins (4 bins/lane) + boundary detect
    if (tid < 64) {
      int h0 = histT[4*tid + 0], h1 = histT[4*tid + 1];
      int h2 = histT[4*tid + 2], h3 = histT[4*tid + 3];
      int tot = h0 + h1 + h2 + h3;
      int suf = tot;
      #pragma unroll
      for (int d = 1; d < 64; d <<= 1) {
        int o = __shfl_down(suf, d);
        if (tid + d < 64) suf += o;
      }
      int above = suf - tot;          // sum over bins > 4*tid+3
      int c3 = h3 + above;
      int c2 = c3 + h2;
      int c1 = c2 + h1;
      int c0 = c1 + h0;
      if      (c3 >= k && above < k) { s_digit = 4*tid+3; s_krem = k - above; s_break = (h3 == 1); }
      else if (c2 >= k && c3    < k) { s_digit = 4*tid+2; s_krem = k - c3;    s_break = (h2 == 1); }
      else if (c1 >= k && c2    < k) { s_digit = 4*tid+1; s_krem = k - c2;    s_break = (h1 == 1); }
      else if (c0 >= k && c1    < k) { s_digit = 4*tid+0; s_krem = k - c1;    s_break = (h0 == 1); }
    }
    __syncthreads();
    prefix |= ((unsigned long long)s_digit) << shift;
    k = s_krem;
    brk = s_break;
  }

  // ---- recover exact threshold key T ----
  if (shift == 0) {
    if (tid == 0) s_T = prefix;
  } else {
    unsigned long long known_mask = ~0ULL << shift;
    #pragma unroll
    for (int r = 0; r < 16; ++r)
      if ((rk[r] & known_mask) == prefix) s_T = rk[r];
  }
  __syncthreads();
  unsigned long long T = s_T;

  // ---- compact the exactly-256 keys >= T (order irrelevant) ----
  #pragma unroll
  for (int r = 0; r < 16; ++r) {
    unsigned long long kk = rk[r];
    if (kk >= T) { int pos = atomicAdd(&s_cnt, 1); s_sel[pos] = kk; }
  }
  __syncthreads();

  // ---- order by rank-by-count ----
  int my_rank = -1, my_v = 0;
  if (tid < NN) {
    unsigned long long mine = s_sel[tid];
    int rank = 0;
    #pragma unroll 16
    for (int j = 0; j < NN; ++j) rank += (s_sel[j] > mine) ? 1 : 0;
    unsigned bits = (unsigned)(mine >> 32);
    int v = bits > 0x3F000000u ? 1 : 0;          // prob > 0.5f strictly
    int idx = (int)(0xFFFFFFFFu - (unsigned)(mine & 0xFFFFFFFFull));
    if (v) atomicAdd(&s_vcnt, 1);
    topi[b*NN + rank] = idx;
    valid[b*NN + rank] = v;
    int iy = idx >> 7;          // w = 128
    int ix = idx & 127;
    float yo = off[((size_t)b*2 + 0) * NPIX + idx];
    float xo = off[((size_t)b*2 + 1) * NPIX + idx];
    out_nodes[(b*NN + rank)*2 + 0] = ((float)ix + 0.5f + xo) * 4.0f;   // STRIDE = 4
    out_nodes[(b*NN + rank)*2 + 1] = ((float)iy + 0.5f + yo) * 4.0f;
    my_rank = rank; my_v = v;
  }
  __syncthreads();
  if (tid < NN) {
    int V = s_vcnt;
    inv_deg[b*NN + my_rank] = (my_v && V >= 2) ? 1.0f / (float)(V - 1) : 0.0f;
  }
}

// ---------------- Kernel 2: gather node features + fused colsum into S0 ----------------
__global__ __launch_bounds__(256) void k_gather(
    const float* __restrict__ nmap, const int* __restrict__ topi,
    const int* __restrict__ valid, float* __restrict__ x, float* __restrict__ S0)
{
  const int bn = blockIdx.x;          // b*256 + n
  const int b = bn >> 8;
  const int c = threadIdx.x;
  int pix = topi[bn];
  int v = valid[bn];
  float val = v ? nmap[(((size_t)b*CC + c) << 14) + pix] : 0.0f;
  x[(size_t)bn*CC + c] = val;
  if (val != 0.0f) atomicAdd(&S0[b*CC + c], val);
}

// ---------------- Kernel 3: fused GNN layer, image-batched GEMM ----------------
// out = relu(x @ Wself + ((S - x)*inv_deg) @ Wnbr + bias) * valid
// Block: 2 rows x 4 images (8 rows share one weight stream), 128 cols, K split 2-way.
// Grid: 128 row-groups x 2 col-halves = 256 blocks, 256 threads.
__global__ __launch_bounds__(256) void k_gnn(
    const float* __restrict__ x, const float* __restrict__ S,
    const float* __restrict__ inv_deg, const int* __restrict__ valid,
    const float* __restrict__ Wself, const float* __restrict__ Wnbr,
    const float* __restrict__ bias, float* __restrict__ xout,
    float* __restrict__ Snext,     // may be null
    float* __restrict__ out_emb)   // may be null
{
  __shared__ float sx[8][CC];      // 8 KiB  [img*2+r][c]
  __shared__ float sz[8][CC];      // 8 KiB
  __shared__ float red[8][128];    // 4 KiB  kh=1 partials
  const int rg  = blockIdx.x >> 1;           // 0..127 row-group
  const int ch  = blockIdx.x & 1;            // column half
  const int n0  = rg * 2;
  const int tid = threadIdx.x;
  const int colh = tid & 127;
  const int col  = (ch << 7) + colh;
  const int kh   = tid >> 7;                 // K half

  #pragma unroll
  for (int rr = 0; rr < 8; ++rr) {
    int b = rr >> 1, r = rr & 1;
    float a = x[((size_t)(b*NN + n0 + r))*CC + tid];
    sx[rr][tid] = a;
    sz[rr][tid] = (S[b*CC + tid] - a) * inv_deg[b*NN + n0 + r];
  }
  __syncthreads();

  float acc[8] = {0,0,0,0,0,0,0,0};
  const int c0 = kh << 7;
  #pragma unroll 4
  for (int ci = 0; ci < 128; ++ci) {
    int c = c0 + ci;
    float w1 = Wself[c*CC + col];
    float w2 = Wnbr[c*CC + col];
    #pragma unroll
    for (int rr = 0; rr < 8; ++rr)
      acc[rr] += sx[rr][c]*w1 + sz[rr][c]*w2;
  }

  if (kh == 1) {
    #pragma unroll
    for (int rr = 0; rr < 8; ++rr) red[rr][colh] = acc[rr];
  }
  __syncthreads();
  if (kh == 0) {
    float bv = bias[col];
    #pragma unroll
    for (int b = 0; b < 4; ++b) {
      float cs = 0.f;
      #pragma unroll
      for (int r = 0; r < 2; ++r) {
        int rr = b*2 + r;
        float o = fmaxf(acc[rr] + red[rr][colh] + bv, 0.f);
        o = valid[b*NN + n0 + r] ? o : 0.f;
        size_t oi = ((size_t)(b*NN + n0 + r))*CC + col;
        xout[oi] = o;
        if (out_emb) out_emb[oi] = o;
        cs += o;
      }
      if (Snext && cs != 0.f) atomicAdd(&Snext[b*CC + col], cs);
    }
  }
}

// ---------------- Kernel 4: u = x@Ws1[:C], v_t = (x@Ws1[C:])^T ----------------
__global__ __launch_bounds__(128) void k_uv(
    const float* __restrict__ x, const float* __restrict__ Ws1,
    float* __restrict__ u, float* __restrict__ vt)
{
  __shared__ float sx[RR][CC];
  const int b = blockIdx.x >> 7;            // 128 row-groups per image
  const int n0 = (blockIdx.x & 127) * RR;
  const int tid = threadIdx.x;              // h
  #pragma unroll
  for (int r = 0; r < RR; ++r)
    for (int c = tid; c < CC; c += 128)
      sx[r][c] = x[((size_t)(b*NN + n0 + r))*CC + c];
  __syncthreads();
  float au0 = 0.f, au1 = 0.f, av0 = 0.f, av1 = 0.f;
  #pragma unroll 8
  for (int c = 0; c < CC; ++c) {
    float w1 = Ws1[c*HH + tid];
    float w2 = Ws1[(CC + c)*HH + tid];
    au0 += sx[0][c]*w1; av0 += sx[0][c]*w2;
    au1 += sx[1][c]*w1; av1 += sx[1][c]*w2;
  }
  u [((size_t)(b*NN + n0 + 0))*HH + tid] = au0;
  u [((size_t)(b*NN + n0 + 1))*HH + tid] = au1;
  vt[((size_t)b*HH + tid)*NN + (n0 + 0)] = av0;
  vt[((size_t)b*HH + tid)*NN + (n0 + 1)] = av1;
}

// ---------------- Kernel 5: per-edge scorer ----------------
__global__ __launch_bounds__(256) void k_edges(
    const float* __restrict__ u, const float* __restrict__ vt,
    const float* __restrict__ bs1, const float* __restrict__ Ws2,
    const float* __restrict__ bs2, const int* __restrict__ valid,
    float* __restrict__ out_logits, float* __restrict__ out_keep)
{
  __shared__ float su[HH], sb1[HH], sw2[HH];
  const int b = blockIdx.x >> 8;
  const int i = blockIdx.x & 255;   // src node
  const int j = threadIdx.x;        // dst node
  if (j < HH) {
    su[j]  = u[((size_t)(b*NN + i))*HH + j];
    sb1[j] = bs1[j];
    sw2[j] = Ws2[j];
  }
  __syncthreads();
  float acc = 0.f;
  const float* vrow = vt + (size_t)b*HH*NN;
  #pragma unroll 8
  for (int h = 0; h < HH; ++h) {
    float t = su[h] + vrow[h*NN + j] + sb1[h];
    acc += fmaxf(t, 0.f) * sw2[h];
  }
  acc += bs2[0];
  if (j != i) {
    int e = i*255 + (j < i ? j : j - 1);
    int ev = valid[b*NN + i] & valid[b*NN + j];
    out_logits[(size_t)b*EE + e] = acc;
    out_keep  [(size_t)b*EE + e] = (acc > 0.f && ev) ? 1.0f : 0.0f;
  }
}

extern "C" void kernel_launch(void* const* d_in, const int* in_sizes, int n_in,
                              void* d_out, int out_size, void* d_ws, size_t ws_size,
                              hipStream_t stream) {
  const float* jl    = (const float*)d_in[0];
  const float* off   = (const float*)d_in[1];
  const float* nmap  = (const float*)d_in[2];
  const float* Wself = (const float*)d_in[3];
  const float* Wnbr  = (const float*)d_in[4];
  const float* bg    = (const float*)d_in[5];
  const float* Ws1   = (const float*)d_in[6];
  const float* bs1   = (const float*)d_in[7];
  const float* Ws2   = (const float*)d_in[8];
  const float* bs2   = (const float*)d_in[9];

  char* ws = (char*)d_ws;
  int*   topi    = (int*)  (ws + 0);                 //  4 KiB
  int*   valid   = (int*)  (ws + 4096);              //  4 KiB
  float* inv_deg = (float*)(ws + 8192);              //  4 KiB
  float* Sbuf    = (float*)(ws + 12288);             // 16 KiB (4 layers' colsums)
  float* xa      = (float*)(ws + 28672);             //  1 MiB
  float* xb      = (float*)(ws + 28672 + 1048576);   //  1 MiB
  float* u       = (float*)(ws + 2125824);           //  512 KiB
  float* vt      = (float*)(ws + 2650112);           //  512 KiB

  float* out        = (float*)d_out;
  float* out_nodes  = out;                  // [4,256,2]   -> 2048
  float* out_emb    = out + 2048;           // [4,256,256] -> 262144
  float* out_logits = out + 264192;         // [4,65280]   -> 261120
  float* out_keep   = out + 525312;         // [4,65280]   -> 261120

  hipLaunchKernelGGL(k_topk,   dim3(BB),     dim3(1024), 0, stream,
                     jl, off, topi, valid, inv_deg, out_nodes, Sbuf);
  hipLaunchKernelGGL(k_gather, dim3(BB*NN),  dim3(256),  0, stream,
                     nmap, topi, valid, xa, Sbuf);

  float* xc = xa; float* xn = xb;
  for (int l = 0; l < 3; ++l) {
    hipLaunchKernelGGL(k_gnn, dim3(256), dim3(256), 0, stream,
                       xc, Sbuf + l*BB*CC, inv_deg, valid,
                       Wself + (size_t)l*CC*CC, Wnbr + (size_t)l*CC*CC, bg + l*CC,
                       xn,
                       (l < 2) ? (Sbuf + (l+1)*BB*CC) : (float*)nullptr,
                       (l == 2) ? out_emb : (float*)nullptr);
    float* t = xc; xc = xn; xn = t;
  }

  hipLaunchKernelGGL(k_uv,    dim3(BB*(NN/RR)), dim3(128), 0, stream, xc, Ws1, u, vt);
  hipLaunchKernelGGL(k_edges, dim3(BB*NN),      dim3(256), 0, stream,
                     u, vt, bs1, Ws2, bs2, valid, out_logits, out_keep);
}

// Round 6
// 129.661 us; speedup vs baseline: 1.3135x; 1.3135x over previous
//
#include <hip/hip_runtime.h>

#define NPIX 16384   // 128*128
#define NN   256     // max_nodes
#define CC   256     // NFEAT
#define HH   128     // SCORER_HIDDEN
#define EE   65280   // NN*(NN-1)
#define BB   4
#define NG   8       // histogram privatization groups
#define RR   2       // rows per thread in k_uv

// ---------------- Kernel 1: sigmoid + exact top-k via register radix select ----------------
// key = (float_bits(prob) << 32) | (0xFFFFFFFF - idx)  -- unique per pixel
// top-256 keys descending => prob desc, ties -> lower idx first (matches jax.lax.top_k)
// Also zeroes Sbuf (4 layer colsum buffers) -- replaces a 39.6us hipMemsetAsync dispatch.
__global__ __launch_bounds__(1024) void k_topk(
    const float* __restrict__ jl, const float* __restrict__ off,
    int* __restrict__ topi, int* __restrict__ valid, float* __restrict__ inv_deg,
    float* __restrict__ out_nodes, float* __restrict__ Sbuf)
{
  __shared__ int hist[NG][257];                 // padded: group copies on distinct banks
  __shared__ int histT[256];
  __shared__ unsigned long long s_sel[NN];
  __shared__ unsigned long long s_T;
  __shared__ int s_digit, s_krem, s_cnt, s_vcnt, s_break;

  const int b = blockIdx.x;
  const int tid = threadIdx.x;
  const int grp = (tid >> 7) & (NG - 1);
  if (tid == 0) { s_cnt = 0; s_vcnt = 0; }

  // zero the 4 colsum buffers for this image (layout: Sbuf[l*BB*CC + b*CC + c])
  {
    int l = tid >> 8, c = tid & 255;
    Sbuf[l*BB*CC + b*CC + c] = 0.0f;
  }

  // ---- keys in registers: 16 per thread, coalesced stride-1024 loads ----
  unsigned long long rk[16];
  const float* p = jl + (size_t)b * NPIX;
  #pragma unroll
  for (int r = 0; r < 16; ++r) {
    int i = tid + (r << 10);
    float x = p[i];
    float pr = 1.0f / (1.0f + expf(-x));
    unsigned bits = __float_as_uint(pr);        // prob in (0,1]: bits monotone
    rk[r] = ((unsigned long long)bits << 32) | (unsigned)(0xFFFFFFFFu - (unsigned)i);
  }

  // ---- radix select: find T = 256th largest key ----
  unsigned long long prefix = 0;
  int k = NN;
  int shift = 56;
  int brk = 0;
  for (int pass = 0; pass < 8 && !brk; ++pass) {
    shift = 56 - 8 * pass;
    for (int i = tid; i < NG * 257; i += 1024) ((int*)hist)[i] = 0;
    __syncthreads();
    unsigned long long pmask = (pass == 0) ? 0ULL : (~0ULL << (shift + 8));
    #pragma unroll
    for (int r = 0; r < 16; ++r) {
      unsigned long long kk = rk[r];
      if ((kk & pmask) == prefix)
        atomicAdd(&hist[grp][(int)((kk >> shift) & 255)], 1);
    }
    __syncthreads();
    if (tid < 256) {
      int t = 0;
      #pragma unroll
      for (int g = 0; g < NG; ++g) t += hist[g][tid];
      histT[tid] = t;
    }
    __syncthreads();
    // wave 0: suffix scan over 256 bins (4 bins/lane) + boundary detect
    if (tid < 64) {
      int h0 = histT[4*tid + 0], h1 = histT[4*tid + 1];
      int h2 = histT[4*tid + 2], h3 = histT[4*tid + 3];
      int tot = h0 + h1 + h2 + h3;
      int suf = tot;
      #pragma unroll
      for (int d = 1; d < 64; d <<= 1) {
        int o = __shfl_down(suf, d);
        if (tid + d < 64) suf += o;
      }
      int above = suf - tot;          // sum over bins > 4*tid+3
      int c3 = h3 + above;
      int c2 = c3 + h2;
      int c1 = c2 + h1;
      int c0 = c1 + h0;
      if      (c3 >= k && above < k) { s_digit = 4*tid+3; s_krem = k - above; s_break = (h3 == 1); }
      else if (c2 >= k && c3    < k) { s_digit = 4*tid+2; s_krem = k - c3;    s_break = (h2 == 1); }
      else if (c1 >= k && c2    < k) { s_digit = 4*tid+1; s_krem = k - c2;    s_break = (h1 == 1); }
      else if (c0 >= k && c1    < k) { s_digit = 4*tid+0; s_krem = k - c1;    s_break = (h0 == 1); }
    }
    __syncthreads();
    prefix |= ((unsigned long long)s_digit) << shift;
    k = s_krem;
    brk = s_break;
  }

  // ---- recover exact threshold key T ----
  if (shift == 0) {
    if (tid == 0) s_T = prefix;
  } else {
    unsigned long long known_mask = ~0ULL << shift;
    #pragma unroll
    for (int r = 0; r < 16; ++r)
      if ((rk[r] & known_mask) == prefix) s_T = rk[r];
  }
  __syncthreads();
  unsigned long long T = s_T;

  // ---- compact the exactly-256 keys >= T (order irrelevant) ----
  #pragma unroll
  for (int r = 0; r < 16; ++r) {
    unsigned long long kk = rk[r];
    if (kk >= T) { int pos = atomicAdd(&s_cnt, 1); s_sel[pos] = kk; }
  }
  __syncthreads();

  // ---- order by rank-by-count ----
  int my_rank = -1, my_v = 0;
  if (tid < NN) {
    unsigned long long mine = s_sel[tid];
    int rank = 0;
    #pragma unroll 16
    for (int j = 0; j < NN; ++j) rank += (s_sel[j] > mine) ? 1 : 0;
    unsigned bits = (unsigned)(mine >> 32);
    int v = bits > 0x3F000000u ? 1 : 0;          // prob > 0.5f strictly
    int idx = (int)(0xFFFFFFFFu - (unsigned)(mine & 0xFFFFFFFFull));
    if (v) atomicAdd(&s_vcnt, 1);
    topi[b*NN + rank] = idx;
    valid[b*NN + rank] = v;
    int iy = idx >> 7;          // w = 128
    int ix = idx & 127;
    float yo = off[((size_t)b*2 + 0) * NPIX + idx];
    float xo = off[((size_t)b*2 + 1) * NPIX + idx];
    out_nodes[(b*NN + rank)*2 + 0] = ((float)ix + 0.5f + xo) * 4.0f;   // STRIDE = 4
    out_nodes[(b*NN + rank)*2 + 1] = ((float)iy + 0.5f + yo) * 4.0f;
    my_rank = rank; my_v = v;
  }
  __syncthreads();
  if (tid < NN) {
    int V = s_vcnt;
    inv_deg[b*NN + my_rank] = (my_v && V >= 2) ? 1.0f / (float)(V - 1) : 0.0f;
  }
}

// ---------------- Kernel 2: gather node features + fused colsum into S0 ----------------
__global__ __launch_bounds__(256) void k_gather(
    const float* __restrict__ nmap, const int* __restrict__ topi,
    const int* __restrict__ valid, float* __restrict__ x, float* __restrict__ S0)
{
  const int bn = blockIdx.x;          // b*256 + n
  const int b = bn >> 8;
  const int c = threadIdx.x;
  int pix = topi[bn];
  int v = valid[bn];
  float val = v ? nmap[(((size_t)b*CC + c) << 14) + pix] : 0.0f;
  x[(size_t)bn*CC + c] = val;
  if (val != 0.0f) atomicAdd(&S0[b*CC + c], val);
}

// ---------------- Kernel 3: fused GNN layer, image-batched + K-split GEMM ----------------
// out = relu(x @ Wself + ((S - x)*inv_deg) @ Wnbr + bias) * valid
// Block: 8 rows (2/image x 4 images) x 32 cols x K-split 8.
// Grid: 128 row-groups x 8 col-slices = 1024 blocks (4/CU), 256 threads.
// Weight traffic: 512KB x 128 rg = 64MB/layer (~2us L2); 512 FMA + 64 loads/thread.
__global__ __launch_bounds__(256) void k_gnn(
    const float* __restrict__ x, const float* __restrict__ S,
    const float* __restrict__ inv_deg, const int* __restrict__ valid,
    const float* __restrict__ Wself, const float* __restrict__ Wnbr,
    const float* __restrict__ bias, float* __restrict__ xout,
    float* __restrict__ Snext,     // may be null
    float* __restrict__ out_emb)   // may be null
{
  __shared__ float sx[8][CC];      // 8 KiB  [img*2+r][c]
  __shared__ float sz[8][CC];      // 8 KiB
  __shared__ float red[8*256];     // 8 KiB  [kway][rr*32+colh]
  const int rg  = blockIdx.x >> 3;           // 0..127 row-group
  const int cs  = blockIdx.x & 7;            // col slice (32 cols)
  const int n0  = rg * 2;
  const int tid = threadIdx.x;
  const int colh = tid & 31;
  const int col  = (cs << 5) + colh;
  const int kw   = tid >> 5;                 // K-way 0..7

  #pragma unroll
  for (int rr = 0; rr < 8; ++rr) {
    int b = rr >> 1, r = rr & 1;
    float a = x[((size_t)(b*NN + n0 + r))*CC + tid];
    sx[rr][tid] = a;
    sz[rr][tid] = (S[b*CC + tid] - a) * inv_deg[b*NN + n0 + r];
  }
  __syncthreads();

  float acc[8] = {0,0,0,0,0,0,0,0};
  const int c0 = kw << 5;
  #pragma unroll 8
  for (int ci = 0; ci < 32; ++ci) {
    int c = c0 + ci;
    float w1 = Wself[c*CC + col];
    float w2 = Wnbr[c*CC + col];
    #pragma unroll
    for (int rr = 0; rr < 8; ++rr)
      acc[rr] += sx[rr][c]*w1 + sz[rr][c]*w2;
  }

  #pragma unroll
  for (int rr = 0; rr < 8; ++rr)
    red[kw*256 + rr*32 + colh] = acc[rr];
  __syncthreads();

  // epilogue: tid = rr*32 + colh  (256 outputs per block)
  {
    int rr = tid >> 5;              // 0..7
    int ch = tid & 31;
    int b = rr >> 1, r = rr & 1;
    int ocol = (cs << 5) + ch;
    float sum = 0.f;
    #pragma unroll
    for (int kk = 0; kk < 8; ++kk) sum += red[kk*256 + tid];
    float o = fmaxf(sum + bias[ocol], 0.f);
    o = valid[b*NN + n0 + r] ? o : 0.f;
    size_t oi = ((size_t)(b*NN + n0 + r))*CC + ocol;
    xout[oi] = o;
    if (out_emb) out_emb[oi] = o;
    if (Snext && o != 0.f) atomicAdd(&Snext[b*CC + ocol], o);
  }
}

// ---------------- Kernel 4: u = x@Ws1[:C], v_t = (x@Ws1[C:])^T ----------------
__global__ __launch_bounds__(128) void k_uv(
    const float* __restrict__ x, const float* __restrict__ Ws1,
    float* __restrict__ u, float* __restrict__ vt)
{
  __shared__ float sx[RR][CC];
  const int b = blockIdx.x >> 7;            // 128 row-groups per image
  const int n0 = (blockIdx.x & 127) * RR;
  const int tid = threadIdx.x;              // h
  #pragma unroll
  for (int r = 0; r < RR; ++r)
    for (int c = tid; c < CC; c += 128)
      sx[r][c] = x[((size_t)(b*NN + n0 + r))*CC + c];
  __syncthreads();
  float au0 = 0.f, au1 = 0.f, av0 = 0.f, av1 = 0.f;
  #pragma unroll 8
  for (int c = 0; c < CC; ++c) {
    float w1 = Ws1[c*HH + tid];
    float w2 = Ws1[(CC + c)*HH + tid];
    au0 += sx[0][c]*w1; av0 += sx[0][c]*w2;
    au1 += sx[1][c]*w1; av1 += sx[1][c]*w2;
  }
  u [((size_t)(b*NN + n0 + 0))*HH + tid] = au0;
  u [((size_t)(b*NN + n0 + 1))*HH + tid] = au1;
  vt[((size_t)b*HH + tid)*NN + (n0 + 0)] = av0;
  vt[((size_t)b*HH + tid)*NN + (n0 + 1)] = av1;
}

// ---------------- Kernel 5: per-edge scorer ----------------
__global__ __launch_bounds__(256) void k_edges(
    const float* __restrict__ u, const float* __restrict__ vt,
    const float* __restrict__ bs1, const float* __restrict__ Ws2,
    const float* __restrict__ bs2, const int* __restrict__ valid,
    float* __restrict__ out_logits, float* __restrict__ out_keep)
{
  __shared__ float su[HH], sb1[HH], sw2[HH];
  const int b = blockIdx.x >> 8;
  const int i = blockIdx.x & 255;   // src node
  const int j = threadIdx.x;        // dst node
  if (j < HH) {
    su[j]  = u[((size_t)(b*NN + i))*HH + j];
    sb1[j] = bs1[j];
    sw2[j] = Ws2[j];
  }
  __syncthreads();
  float acc = 0.f;
  const float* vrow = vt + (size_t)b*HH*NN;
  #pragma unroll 8
  for (int h = 0; h < HH; ++h) {
    float t = su[h] + vrow[h*NN + j] + sb1[h];
    acc += fmaxf(t, 0.f) * sw2[h];
  }
  acc += bs2[0];
  if (j != i) {
    int e = i*255 + (j < i ? j : j - 1);
    int ev = valid[b*NN + i] & valid[b*NN + j];
    out_logits[(size_t)b*EE + e] = acc;
    out_keep  [(size_t)b*EE + e] = (acc > 0.f && ev) ? 1.0f : 0.0f;
  }
}

extern "C" void kernel_launch(void* const* d_in, const int* in_sizes, int n_in,
                              void* d_out, int out_size, void* d_ws, size_t ws_size,
                              hipStream_t stream) {
  const float* jl    = (const float*)d_in[0];
  const float* off   = (const float*)d_in[1];
  const float* nmap  = (const float*)d_in[2];
  const float* Wself = (const float*)d_in[3];
  const float* Wnbr  = (const float*)d_in[4];
  const float* bg    = (const float*)d_in[5];
  const float* Ws1   = (const float*)d_in[6];
  const float* bs1   = (const float*)d_in[7];
  const float* Ws2   = (const float*)d_in[8];
  const float* bs2   = (const float*)d_in[9];

  char* ws = (char*)d_ws;
  int*   topi    = (int*)  (ws + 0);                 //  4 KiB
  int*   valid   = (int*)  (ws + 4096);              //  4 KiB
  float* inv_deg = (float*)(ws + 8192);              //  4 KiB
  float* Sbuf    = (float*)(ws + 12288);             // 16 KiB (4 layers' colsums)
  float* xa      = (float*)(ws + 28672);             //  1 MiB
  float* xb      = (float*)(ws + 28672 + 1048576);   //  1 MiB
  float* u       = (float*)(ws + 2125824);           //  512 KiB
  float* vt      = (float*)(ws + 2650112);           //  512 KiB

  float* out        = (float*)d_out;
  float* out_nodes  = out;                  // [4,256,2]   -> 2048
  float* out_emb    = out + 2048;           // [4,256,256] -> 262144
  float* out_logits = out + 264192;         // [4,65280]   -> 261120
  float* out_keep   = out + 525312;         // [4,65280]   -> 261120

  hipLaunchKernelGGL(k_topk,   dim3(BB),     dim3(1024), 0, stream,
                     jl, off, topi, valid, inv_deg, out_nodes, Sbuf);
  hipLaunchKernelGGL(k_gather, dim3(BB*NN),  dim3(256),  0, stream,
                     nmap, topi, valid, xa, Sbuf);

  float* xc = xa; float* xn = xb;
  for (int l = 0; l < 3; ++l) {
    hipLaunchKernelGGL(k_gnn, dim3(1024), dim3(256), 0, stream,
                       xc, Sbuf + l*BB*CC, inv_deg, valid,
                       Wself + (size_t)l*CC*CC, Wnbr + (size_t)l*CC*CC, bg + l*CC,
                       xn,
                       (l < 2) ? (Sbuf + (l+1)*BB*CC) : (float*)nullptr,
                       (l == 2) ? out_emb : (float*)nullptr);
    float* t = xc; xc = xn; xn = t;
  }

  hipLaunchKernelGGL(k_uv,    dim3(BB*(NN/RR)), dim3(128), 0, stream, xc, Ws1, u, vt);
  hipLaunchKernelGGL(k_edges, dim3(BB*NN),      dim3(256), 0, stream,
                     u, vt, bs1, Ws2, bs2, valid, out_logits, out_keep);
}

// Round 7
// 129.059 us; speedup vs baseline: 1.3196x; 1.0047x over previous
//
#include <hip/hip_runtime.h>

#define NPIX 16384   // 128*128
#define NN   256     // max_nodes
#define CC   256     // NFEAT
#define HH   128     // SCORER_HIDDEN
#define EE   65280   // NN*(NN-1)
#define BB   4
#define NG   8       // histogram privatization groups

// ---------------- Kernel 1: sigmoid + exact top-k via register radix select ----------------
// key = (float_bits(prob) << 32) | (0xFFFFFFFF - idx)  -- unique per pixel
// top-256 keys descending => prob desc, ties -> lower idx first (matches jax.lax.top_k)
// Also zeroes Sbuf (4 layer colsum buffers).
__global__ __launch_bounds__(1024) void k_topk(
    const float* __restrict__ jl, const float* __restrict__ off,
    int* __restrict__ topi, int* __restrict__ valid, float* __restrict__ inv_deg,
    float* __restrict__ out_nodes, float* __restrict__ Sbuf)
{
  __shared__ int hist[NG][257];                 // padded: group copies on distinct banks
  __shared__ int histT[256];
  __shared__ unsigned long long s_sel[NN];
  __shared__ unsigned long long s_T;
  __shared__ int s_digit, s_krem, s_cnt, s_vcnt, s_break;

  const int b = blockIdx.x;
  const int tid = threadIdx.x;
  const int grp = (tid >> 7) & (NG - 1);
  if (tid == 0) { s_cnt = 0; s_vcnt = 0; }

  // zero the 4 colsum buffers for this image (layout: Sbuf[l*BB*CC + b*CC + c])
  {
    int l = tid >> 8, c = tid & 255;
    Sbuf[l*BB*CC + b*CC + c] = 0.0f;
  }

  // ---- keys in registers: 16 per thread, coalesced stride-1024 loads ----
  unsigned long long rk[16];
  const float* p = jl + (size_t)b * NPIX;
  #pragma unroll
  for (int r = 0; r < 16; ++r) {
    int i = tid + (r << 10);
    float x = p[i];
    float pr = 1.0f / (1.0f + expf(-x));
    unsigned bits = __float_as_uint(pr);        // prob in (0,1]: bits monotone
    rk[r] = ((unsigned long long)bits << 32) | (unsigned)(0xFFFFFFFFu - (unsigned)i);
  }

  // ---- radix select: find T = 256th largest key ----
  unsigned long long prefix = 0;
  int k = NN;
  int shift = 56;
  int brk = 0;
  for (int pass = 0; pass < 8 && !brk; ++pass) {
    shift = 56 - 8 * pass;
    for (int i = tid; i < NG * 257; i += 1024) ((int*)hist)[i] = 0;
    __syncthreads();
    unsigned long long pmask = (pass == 0) ? 0ULL : (~0ULL << (shift + 8));
    #pragma unroll
    for (int r = 0; r < 16; ++r) {
      unsigned long long kk = rk[r];
      if ((kk & pmask) == prefix)
        atomicAdd(&hist[grp][(int)((kk >> shift) & 255)], 1);
    }
    __syncthreads();
    if (tid < 256) {
      int t = 0;
      #pragma unroll
      for (int g = 0; g < NG; ++g) t += hist[g][tid];
      histT[tid] = t;
    }
    __syncthreads();
    // wave 0: suffix scan over 256 bins (4 bins/lane) + boundary detect
    if (tid < 64) {
      int h0 = histT[4*tid + 0], h1 = histT[4*tid + 1];
      int h2 = histT[4*tid + 2], h3 = histT[4*tid + 3];
      int tot = h0 + h1 + h2 + h3;
      int suf = tot;
      #pragma unroll
      for (int d = 1; d < 64; d <<= 1) {
        int o = __shfl_down(suf, d);
        if (tid + d < 64) suf += o;
      }
      int above = suf - tot;          // sum over bins > 4*tid+3
      int c3 = h3 + above;
      int c2 = c3 + h2;
      int c1 = c2 + h1;
      int c0 = c1 + h0;
      if      (c3 >= k && above < k) { s_digit = 4*tid+3; s_krem = k - above; s_break = (h3 == 1); }
      else if (c2 >= k && c3    < k) { s_digit = 4*tid+2; s_krem = k - c3;    s_break = (h2 == 1); }
      else if (c1 >= k && c2    < k) { s_digit = 4*tid+1; s_krem = k - c2;    s_break = (h1 == 1); }
      else if (c0 >= k && c1    < k) { s_digit = 4*tid+0; s_krem = k - c1;    s_break = (h0 == 1); }
    }
    __syncthreads();
    prefix |= ((unsigned long long)s_digit) << shift;
    k = s_krem;
    brk = s_break;
  }

  // ---- recover exact threshold key T ----
  if (shift == 0) {
    if (tid == 0) s_T = prefix;
  } else {
    unsigned long long known_mask = ~0ULL << shift;
    #pragma unroll
    for (int r = 0; r < 16; ++r)
      if ((rk[r] & known_mask) == prefix) s_T = rk[r];
  }
  __syncthreads();
  unsigned long long T = s_T;

  // ---- compact the exactly-256 keys >= T (order irrelevant) ----
  #pragma unroll
  for (int r = 0; r < 16; ++r) {
    unsigned long long kk = rk[r];
    if (kk >= T) { int pos = atomicAdd(&s_cnt, 1); s_sel[pos] = kk; }
  }
  __syncthreads();

  // ---- order by rank-by-count ----
  int my_rank = -1, my_v = 0;
  if (tid < NN) {
    unsigned long long mine = s_sel[tid];
    int rank = 0;
    #pragma unroll 16
    for (int j = 0; j < NN; ++j) rank += (s_sel[j] > mine) ? 1 : 0;
    unsigned bits = (unsigned)(mine >> 32);
    int v = bits > 0x3F000000u ? 1 : 0;          // prob > 0.5f strictly
    int idx = (int)(0xFFFFFFFFu - (unsigned)(mine & 0xFFFFFFFFull));
    if (v) atomicAdd(&s_vcnt, 1);
    topi[b*NN + rank] = idx;
    valid[b*NN + rank] = v;
    int iy = idx >> 7;          // w = 128
    int ix = idx & 127;
    float yo = off[((size_t)b*2 + 0) * NPIX + idx];
    float xo = off[((size_t)b*2 + 1) * NPIX + idx];
    out_nodes[(b*NN + rank)*2 + 0] = ((float)ix + 0.5f + xo) * 4.0f;   // STRIDE = 4
    out_nodes[(b*NN + rank)*2 + 1] = ((float)iy + 0.5f + yo) * 4.0f;
    my_rank = rank; my_v = v;
  }
  __syncthreads();
  if (tid < NN) {
    int V = s_vcnt;
    inv_deg[b*NN + my_rank] = (my_v && V >= 2) ? 1.0f / (float)(V - 1) : 0.0f;
  }
}

// ---------------- Kernel 2: gather node features + fused colsum into S0 ----------------
__global__ __launch_bounds__(256) void k_gather(
    const float* __restrict__ nmap, const int* __restrict__ topi,
    const int* __restrict__ valid, float* __restrict__ x, float* __restrict__ S0)
{
  const int bn = blockIdx.x;          // b*256 + n
  const int b = bn >> 8;
  const int c = threadIdx.x;
  int pix = topi[bn];
  int v = valid[bn];
  float val = v ? nmap[(((size_t)b*CC + c) << 14) + pix] : 0.0f;
  x[(size_t)bn*CC + c] = val;
  if (val != 0.0f) atomicAdd(&S0[b*CC + c], val);
}

// ---------------- Kernel 3a: P2[b][col] = sum_c S[b][c] * Wnbr[c][col] ----------------
// grid BB, block 1024 = 4 K-ways x 256 cols.
__global__ __launch_bounds__(1024) void k_p2(
    const float* __restrict__ S, const float* __restrict__ Wnbr,
    float* __restrict__ P2)
{
  __shared__ float red[3][256];
  const int b = blockIdx.x;
  const int tid = threadIdx.x;
  const int col = tid & 255;
  const int kw  = tid >> 8;          // 0..3, 64 c's each
  const float4* S4 = (const float4*)(S + b*CC);   // wave-uniform loads
  float acc = 0.f;
  #pragma unroll 4
  for (int c4 = 0; c4 < 16; ++c4) {
    float4 sv = S4[kw*16 + c4];
    int cbase = kw*64 + c4*4;
    acc += sv.x * Wnbr[(size_t)(cbase+0)*CC + col];
    acc += sv.y * Wnbr[(size_t)(cbase+1)*CC + col];
    acc += sv.z * Wnbr[(size_t)(cbase+2)*CC + col];
    acc += sv.w * Wnbr[(size_t)(cbase+3)*CC + col];
  }
  if (kw > 0) red[kw-1][col] = acc;
  __syncthreads();
  if (kw == 0)
    P2[b*CC + col] = acc + red[0][col] + red[1][col] + red[2][col];
}

// ---------------- Kernel 3b: GNN layer, LDS-free main loop ----------------
// out[r][col] = relu(A1 + inv_r*(P2[col] - A2) + bias) * valid
//   A1 = sum_c x[r][c]*Wself[c][col], A2 = sum_c x[r][c]*Wnbr[c][col]
// Block: 4 rows (one image) x 256 cols x K-split 2 = 512 threads. Grid 4*64 = 256.
// x read via wave-uniform float4 (scalar path); weights coalesced; no LDS in loop.
__global__ __launch_bounds__(512) void k_gnn(
    const float* __restrict__ x, const float* __restrict__ P2,
    const float* __restrict__ inv_deg, const int* __restrict__ valid,
    const float* __restrict__ Wself, const float* __restrict__ Wnbr,
    const float* __restrict__ bias, float* __restrict__ xout,
    float* __restrict__ Snext,     // may be null
    float* __restrict__ out_emb)   // may be null
{
  __shared__ float red[8][256];    // 8 KiB, kw=1 partials
  const int b   = blockIdx.x >> 6;
  const int n0  = (blockIdx.x & 63) * 4;
  const int tid = threadIdx.x;
  const int col = tid & 255;
  const int kw  = tid >> 8;        // 0/1, 128 c's each

  const float4* x4 = (const float4*)(x + ((size_t)(b*NN + n0))*CC);
  float a10=0,a11=0,a12=0,a13=0;   // A1 rows 0..3
  float a20=0,a21=0,a22=0,a23=0;   // A2 rows 0..3
  const int q0 = kw << 5;          // float4 chunk base (32 chunks = 128 c's)
  #pragma unroll 2
  for (int c4 = 0; c4 < 32; ++c4) {
    int q = q0 + c4;
    float4 xv0 = x4[0*64 + q];
    float4 xv1 = x4[1*64 + q];
    float4 xv2 = x4[2*64 + q];
    float4 xv3 = x4[3*64 + q];
    int cbase = q << 2;
    #pragma unroll
    for (int e = 0; e < 4; ++e) {
      float w1 = Wself[(size_t)(cbase+e)*CC + col];
      float w2 = Wnbr [(size_t)(cbase+e)*CC + col];
      float x0 = ((const float*)&xv0)[e];
      float x1 = ((const float*)&xv1)[e];
      float x2 = ((const float*)&xv2)[e];
      float x3 = ((const float*)&xv3)[e];
      a10 += x0*w1; a20 += x0*w2;
      a11 += x1*w1; a21 += x1*w2;
      a12 += x2*w1; a22 += x2*w2;
      a13 += x3*w1; a23 += x3*w2;
    }
  }

  if (kw == 1) {
    red[0][col]=a10; red[1][col]=a11; red[2][col]=a12; red[3][col]=a13;
    red[4][col]=a20; red[5][col]=a21; red[6][col]=a22; red[7][col]=a23;
  }
  __syncthreads();
  if (kw == 0) {
    float pv = P2[b*CC + col];
    float bv = bias[col];
    float A1[4] = {a10+red[0][col], a11+red[1][col], a12+red[2][col], a13+red[3][col]};
    float A2[4] = {a20+red[4][col], a21+red[5][col], a22+red[6][col], a23+red[7][col]};
    float cs = 0.f;
    #pragma unroll
    for (int r = 0; r < 4; ++r) {
      float inv = inv_deg[b*NN + n0 + r];
      float o = fmaxf(A1[r] + inv*(pv - A2[r]) + bv, 0.f);
      o = valid[b*NN + n0 + r] ? o : 0.f;
      size_t oi = ((size_t)(b*NN + n0 + r))*CC + col;
      xout[oi] = o;
      if (out_emb) out_emb[oi] = o;
      cs += o;
    }
    if (Snext && cs != 0.f) atomicAdd(&Snext[b*CC + col], cs);
  }
}

// ---------------- Kernel 4: u = x@Ws1[:C], v_t = (x@Ws1[C:])^T, LDS-free loop ----------------
// Block: 4 rows x 128 h x K-split 4 = 512 threads. Grid 4*64 = 256.
__global__ __launch_bounds__(512) void k_uv(
    const float* __restrict__ x, const float* __restrict__ Ws1,
    float* __restrict__ u, float* __restrict__ vt)
{
  __shared__ float red[3][8][128];   // 12 KiB
  const int b   = blockIdx.x >> 6;
  const int n0  = (blockIdx.x & 63) * 4;
  const int tid = threadIdx.x;
  const int h   = tid & 127;
  const int kw  = tid >> 7;          // 0..3, 64 c's each

  const float4* x4 = (const float4*)(x + ((size_t)(b*NN + n0))*CC);
  float au0=0,au1=0,au2=0,au3=0, av0=0,av1=0,av2=0,av3=0;
  #pragma unroll 2
  for (int c4 = 0; c4 < 16; ++c4) {
    int q = kw*16 + c4;
    float4 xv0 = x4[0*64 + q];
    float4 xv1 = x4[1*64 + q];
    float4 xv2 = x4[2*64 + q];
    float4 xv3 = x4[3*64 + q];
    int cbase = q << 2;
    #pragma unroll
    for (int e = 0; e < 4; ++e) {
      float w1 = Ws1[(size_t)(cbase+e)*HH + h];
      float w2 = Ws1[(size_t)(256+cbase+e)*HH + h];
      float x0 = ((const float*)&xv0)[e];
      float x1 = ((const float*)&xv1)[e];
      float x2 = ((const float*)&xv2)[e];
      float x3 = ((const float*)&xv3)[e];
      au0 += x0*w1; av0 += x0*w2;
      au1 += x1*w1; av1 += x1*w2;
      au2 += x2*w1; av2 += x2*w2;
      au3 += x3*w1; av3 += x3*w2;
    }
  }
  if (kw > 0) {
    float* rr = &red[kw-1][0][h];
    rr[0*128]=au0; rr[1*128]=au1; rr[2*128]=au2; rr[3*128]=au3;
    rr[4*128]=av0; rr[5*128]=av1; rr[6*128]=av2; rr[7*128]=av3;
  }
  __syncthreads();
  if (kw == 0) {
    float AU[4] = {au0,au1,au2,au3};
    float AV[4] = {av0,av1,av2,av3};
    #pragma unroll
    for (int g = 0; g < 3; ++g) {
      #pragma unroll
      for (int r = 0; r < 4; ++r) {
        AU[r] += red[g][r][h];
        AV[r] += red[g][4+r][h];
      }
    }
    #pragma unroll
    for (int r = 0; r < 4; ++r) {
      u [((size_t)(b*NN + n0 + r))*HH + h] = AU[r];
      vt[((size_t)b*HH + h)*NN + (n0 + r)] = AV[r];
    }
  }
}

// ---------------- Kernel 5: per-edge scorer, LDS-free (u-row/bs1/Ws2 wave-uniform) ----------------
__global__ __launch_bounds__(256) void k_edges(
    const float* __restrict__ u, const float* __restrict__ vt,
    const float* __restrict__ bs1, const float* __restrict__ Ws2,
    const float* __restrict__ bs2, const int* __restrict__ valid,
    float* __restrict__ out_logits, float* __restrict__ out_keep)
{
  const int b = blockIdx.x >> 8;
  const int i = blockIdx.x & 255;   // src node
  const int j = threadIdx.x;        // dst node
  const float4* u4  = (const float4*)(u + ((size_t)(b*NN + i))*HH);
  const float4* b14 = (const float4*)bs1;
  const float4* w24 = (const float4*)Ws2;
  const float* vrow = vt + (size_t)b*HH*NN;
  float acc = 0.f;
  #pragma unroll 4
  for (int h4 = 0; h4 < 32; ++h4) {
    float4 uu = u4[h4];
    float4 bb = b14[h4];
    float4 ww = w24[h4];
    int hb = h4 << 2;
    float t0 = uu.x + bb.x + vrow[(size_t)(hb+0)*NN + j];
    float t1 = uu.y + bb.y + vrow[(size_t)(hb+1)*NN + j];
    float t2 = uu.z + bb.z + vrow[(size_t)(hb+2)*NN + j];
    float t3 = uu.w + bb.w + vrow[(size_t)(hb+3)*NN + j];
    acc += fmaxf(t0, 0.f)*ww.x + fmaxf(t1, 0.f)*ww.y
         + fmaxf(t2, 0.f)*ww.z + fmaxf(t3, 0.f)*ww.w;
  }
  acc += bs2[0];
  if (j != i) {
    int e = i*255 + (j < i ? j : j - 1);
    int ev = valid[b*NN + i] & valid[b*NN + j];
    out_logits[(size_t)b*EE + e] = acc;
    out_keep  [(size_t)b*EE + e] = (acc > 0.f && ev) ? 1.0f : 0.0f;
  }
}

extern "C" void kernel_launch(void* const* d_in, const int* in_sizes, int n_in,
                              void* d_out, int out_size, void* d_ws, size_t ws_size,
                              hipStream_t stream) {
  const float* jl    = (const float*)d_in[0];
  const float* off   = (const float*)d_in[1];
  const float* nmap  = (const float*)d_in[2];
  const float* Wself = (const float*)d_in[3];
  const float* Wnbr  = (const float*)d_in[4];
  const float* bg    = (const float*)d_in[5];
  const float* Ws1   = (const float*)d_in[6];
  const float* bs1   = (const float*)d_in[7];
  const float* Ws2   = (const float*)d_in[8];
  const float* bs2   = (const float*)d_in[9];

  char* ws = (char*)d_ws;
  int*   topi    = (int*)  (ws + 0);                 //  4 KiB
  int*   valid   = (int*)  (ws + 4096);              //  4 KiB
  float* inv_deg = (float*)(ws + 8192);              //  4 KiB
  float* Sbuf    = (float*)(ws + 12288);             // 16 KiB (layer colsums)
  float* P2      = (float*)(ws + 28672);             //  4 KiB
  float* xa      = (float*)(ws + 32768);             //  1 MiB
  float* xb      = (float*)(ws + 32768 + 1048576);   //  1 MiB
  float* u       = (float*)(ws + 2129920);           //  512 KiB
  float* vt      = (float*)(ws + 2654208);           //  512 KiB

  float* out        = (float*)d_out;
  float* out_nodes  = out;                  // [4,256,2]   -> 2048
  float* out_emb    = out + 2048;           // [4,256,256] -> 262144
  float* out_logits = out + 264192;         // [4,65280]   -> 261120
  float* out_keep   = out + 525312;         // [4,65280]   -> 261120

  hipLaunchKernelGGL(k_topk,   dim3(BB),     dim3(1024), 0, stream,
                     jl, off, topi, valid, inv_deg, out_nodes, Sbuf);
  hipLaunchKernelGGL(k_gather, dim3(BB*NN),  dim3(256),  0, stream,
                     nmap, topi, valid, xa, Sbuf);

  float* xc = xa; float* xn = xb;
  for (int l = 0; l < 3; ++l) {
    hipLaunchKernelGGL(k_p2,  dim3(BB),  dim3(1024), 0, stream,
                       Sbuf + l*BB*CC, Wnbr + (size_t)l*CC*CC, P2);
    hipLaunchKernelGGL(k_gnn, dim3(256), dim3(512),  0, stream,
                       xc, P2, inv_deg, valid,
                       Wself + (size_t)l*CC*CC, Wnbr + (size_t)l*CC*CC, bg + l*CC,
                       xn,
                       (l < 2) ? (Sbuf + (l+1)*BB*CC) : (float*)nullptr,
                       (l == 2) ? out_emb : (float*)nullptr);
    float* t = xc; xc = xn; xn = t;
  }

  hipLaunchKernelGGL(k_uv,    dim3(256),   dim3(512), 0, stream, xc, Ws1, u, vt);
  hipLaunchKernelGGL(k_edges, dim3(BB*NN), dim3(256), 0, stream,
                     u, vt, bs1, Ws2, bs2, valid, out_logits, out_keep);
}